// Round 1
// 147.393 us; speedup vs baseline: 1.0477x; 1.0477x over previous
//
#include <hip/hip_runtime.h>
#include <hip/hip_bf16.h>

typedef unsigned short u16;
typedef unsigned int u32;
typedef __attribute__((ext_vector_type(8))) short short8;
typedef __attribute__((ext_vector_type(4))) float floatx4;

#define NU 16384
#define DIM 256
#define AMS 208               // Am LDS row stride (u16)
#define ACS 200               // Ac LDS row stride (u16) — 400B = 25x16B, 2-way-free
#define ACM 12800             // 64 * ACS

// ws layout (u16 offsets)
#define XHo 0u
#define XLo 4194304u
#define XRo 8388608u
#define YHo 12582912u
#define YLo 16777216u
#define ST0 20971520u
#define STROW 16512u          // 64 guard + 16384 + 64 guard
#define STMAT 4227072u        // 256 * STROW
#define WH0o 33652736u        // ST0 + 3*STMAT
#define WL0o 33718272u
#define WRo  33783808u        // 3 mats x 65536

__device__ __forceinline__ u16 bfh(float v) {            // truncate to bf16
  return (u16)(__float_as_uint(v) >> 16);
}
__device__ __forceinline__ float bup(u16 u) {
  return __uint_as_float(((u32)u) << 16);
}
__device__ __forceinline__ u16 bfrn(float v) {           // round-nearest-even
  u32 u = __float_as_uint(v);
  return (u16)((u + 0x7fffu + ((u >> 16) & 1u)) >> 16);
}

// async global->LDS 16B (linear wave dest: base + lane*16)
__device__ __forceinline__ void gload16(const u16* g, u16* l) {
  __builtin_amdgcn_global_load_lds(
      (__attribute__((address_space(1))) void*)(uintptr_t)g,
      (__attribute__((address_space(3))) void*)(uintptr_t)l, 16, 0, 0);
}

// ---------------------------------------------------------------------------
// xprep: xh/xl (split) + xr (rounded) bf16 copies of x. 8 elems/thread.
// ---------------------------------------------------------------------------
__global__ __launch_bounds__(256) void xprep(const float* __restrict__ x,
                                             u16* __restrict__ ws) {
  int idx = (blockIdx.x * 256 + threadIdx.x) * 8;
  float4 v0 = *(const float4*)(x + idx);
  float4 v1 = *(const float4*)(x + idx + 4);
  float a[8] = {v0.x, v0.y, v0.z, v0.w, v1.x, v1.y, v1.z, v1.w};
  u16 h[8], l[8], r[8];
#pragma unroll
  for (int q = 0; q < 8; ++q) {
    h[q] = bfh(a[q]);
    l[q] = bfh(a[q] - bup(h[q]));
    r[q] = bfrn(a[q]);
  }
  *(uint4*)(ws + XHo + idx) = *(const uint4*)h;
  *(uint4*)(ws + XLo + idx) = *(const uint4*)l;
  *(uint4*)(ws + XRo + idx) = *(const uint4*)r;
}

// ---------------------------------------------------------------------------
// wpgz: blocks 0-31 weight imaging ([s][n][k] order); blocks 32-127 S^T
// guard zeroing.
// ---------------------------------------------------------------------------
__global__ __launch_bounds__(256) void wpgz(
    const float* __restrict__ wat, const float* __restrict__ wpr,
    const float* __restrict__ wsu, const float* __restrict__ wsm,
    const float* __restrict__ wdf, u16* __restrict__ ws) {
  const int b = blockIdx.x, t = threadIdx.x;
  if (b < 32) {
    const int s = b & 7, mat = b >> 3, n = t;
    const float* Wa = (mat == 0) ? wat : (mat == 1) ? wpr : (mat == 2) ? wsm : wsu;
    const float* Wb = (mat == 0) ? wat : (mat == 1) ? wsu : (mat == 2) ? wdf : wdf;
    const float c1  = (mat == 0) ? 0.f : (mat == 3) ? 1.f : -1.f;
    u16 hbuf[32], lbuf[32];
#pragma unroll 8
    for (int k = 0; k < 32; ++k) {
      float v = Wa[(s * 32 + k) * 256 + n] + c1 * Wb[(s * 32 + k) * 256 + n];
      if (mat == 0) { hbuf[k] = bfh(v); lbuf[k] = bfh(v - bup(hbuf[k])); }
      else          { hbuf[k] = bfrn(v); }
    }
    u16* dh = ws + ((mat == 0) ? WH0o : (WRo + (size_t)(mat - 1) * 65536))
               + (size_t)s * 8192 + n * 32;
#pragma unroll
    for (int p = 0; p < 4; ++p) *(uint4*)(dh + p * 8) = ((const uint4*)hbuf)[p];
    if (mat == 0) {
      u16* dl = ws + WL0o + (size_t)s * 8192 + n * 32;
#pragma unroll
      for (int p = 0; p < 4; ++p) *(uint4*)(dl + p * 8) = ((const uint4*)lbuf)[p];
    }
  } else {
    int g = (b - 32) * 256 + t;                    // 24576 threads
    int r = g >> 13, rem = g & 8191;
    int d = rem >> 5, p = rem & 31;
    size_t base = ST0 + (size_t)r * STMAT + (size_t)d * STROW;
    size_t off = (p < 16) ? (base + p * 4) : (base + 16448 + (p - 16) * 4);
    *(ushort4*)(ws + off) = make_ushort4(0, 0, 0, 0);
  }
}

// ---------------------------------------------------------------------------
// gemmS: grid (256, 2). path0: y=x@W_att split 3-MFMA -> yh/yl.
// path1: S1..S3 single-MFMA -> S^T. A-strip staged ONCE (stride 264,
// conflict-free); W fragments read direct from L2-resident images;
// K-loops barrier-free.
// ---------------------------------------------------------------------------
__global__ __launch_bounds__(512) void gemmS(u16* __restrict__ ws) {
  __shared__ __align__(16) u16 U[37888];   // p0: Ah@0 Al@16896 ; p1: Ar@0 Ct@16896

  const int t = threadIdx.x, path = blockIdx.y, row0 = blockIdx.x * 64;
  const int w = t >> 6, ln = t & 15, quad = (t & 63) >> 4, q8 = quad * 8;
  const int n0 = w * 32;

  if (path == 0) {
    // ---- stage xh/xl strip [64][256] -> stride 264 ----
#pragma unroll
    for (int cc = 0; cc < 8; ++cc) {
      int idx = t + 512 * cc;                  // 0..4095
      int buf = idx >> 11, e = idx & 2047;
      int row = e >> 5, c8 = (e & 31) * 8;
      *(uint4*)(U + buf * 16896 + row * 264 + c8) =
          *(const uint4*)(ws + (buf ? XLo : XHo) + (size_t)(row0 + row) * 256 + c8);
    }
    __syncthreads();

    floatx4 acc[4][2];
#pragma unroll
    for (int m = 0; m < 4; ++m)
#pragma unroll
      for (int nt = 0; nt < 2; ++nt) acc[m][nt] = (floatx4){0.f, 0.f, 0.f, 0.f};

    for (int s = 0; s < 8; ++s) {
      short8 ah[4], al[4];
#pragma unroll
      for (int m = 0; m < 4; ++m) {
        ah[m] = *(const short8*)(U + (m * 16 + ln) * 264 + s * 32 + q8);
        al[m] = *(const short8*)(U + 16896 + (m * 16 + ln) * 264 + s * 32 + q8);
      }
      short8 bh[2], bl[2];
#pragma unroll
      for (int nt = 0; nt < 2; ++nt) {
        size_t off = (size_t)s * 8192 + (n0 + nt * 16 + ln) * 32 + q8;
        bh[nt] = *(const short8*)(ws + WH0o + off);
        bl[nt] = *(const short8*)(ws + WL0o + off);
      }
#pragma unroll
      for (int m = 0; m < 4; ++m)
#pragma unroll
        for (int nt = 0; nt < 2; ++nt) {
          acc[m][nt] = __builtin_amdgcn_mfma_f32_16x16x32_bf16(ah[m], bh[nt], acc[m][nt], 0, 0, 0);
          acc[m][nt] = __builtin_amdgcn_mfma_f32_16x16x32_bf16(ah[m], bl[nt], acc[m][nt], 0, 0, 0);
          acc[m][nt] = __builtin_amdgcn_mfma_f32_16x16x32_bf16(al[m], bh[nt], acc[m][nt], 0, 0, 0);
        }
    }
#pragma unroll
    for (int m = 0; m < 4; ++m)
#pragma unroll
      for (int nt = 0; nt < 2; ++nt) {
        int col = n0 + nt * 16 + ln;
#pragma unroll
        for (int r = 0; r < 4; ++r) {
          int row = row0 + m * 16 + quad * 4 + r;
          float y = acc[m][nt][r];
          u16 hh = bfh(y);
          ws[YHo + (size_t)row * 256 + col] = hh;
          ws[YLo + (size_t)row * 256 + col] = bfh(y - bup(hh));
        }
      }
  } else {
    // ---- stage xr strip ----
#pragma unroll
    for (int cc = 0; cc < 4; ++cc) {
      int idx = t + 512 * cc;                  // 0..2047
      int row = idx >> 5, c8 = (idx & 31) * 8;
      *(uint4*)(U + row * 264 + c8) =
          *(const uint4*)(ws + XRo + (size_t)(row0 + row) * 256 + c8);
    }
    __syncthreads();

    for (int mat = 0; mat < 3; ++mat) {
      floatx4 acc[4][2];
#pragma unroll
      for (int m = 0; m < 4; ++m)
#pragma unroll
        for (int nt = 0; nt < 2; ++nt) acc[m][nt] = (floatx4){0.f, 0.f, 0.f, 0.f};
      for (int s = 0; s < 8; ++s) {
        short8 ah[4];
#pragma unroll
        for (int m = 0; m < 4; ++m)
          ah[m] = *(const short8*)(U + (m * 16 + ln) * 264 + s * 32 + q8);
        short8 bh[2];
#pragma unroll
        for (int nt = 0; nt < 2; ++nt)
          bh[nt] = *(const short8*)(ws + WRo + (size_t)mat * 65536
                                    + (size_t)s * 8192 + (n0 + nt * 16 + ln) * 32 + q8);
#pragma unroll
        for (int m = 0; m < 4; ++m)
#pragma unroll
          for (int nt = 0; nt < 2; ++nt)
            acc[m][nt] = __builtin_amdgcn_mfma_f32_16x16x32_bf16(ah[m], bh[nt], acc[m][nt], 0, 0, 0);
      }
      __syncthreads();                           // Ct reuse guard
#pragma unroll
      for (int m = 0; m < 4; ++m)
#pragma unroll
        for (int nt = 0; nt < 2; ++nt) {
          int col = n0 + nt * 16 + ln;
          ushort4 pk = make_ushort4(bfrn(acc[m][nt][0]), bfrn(acc[m][nt][1]),
                                    bfrn(acc[m][nt][2]), bfrn(acc[m][nt][3]));
          *(ushort4*)(U + 16896 + col * 80 + m * 16 + quad * 4) = pk;
        }
      __syncthreads();
      u16* STm = ws + ST0 + (size_t)mat * STMAT;
#pragma unroll
      for (int cc = 0; cc < 4; ++cc) {
        int c = t + 512 * cc;
        int d = c >> 3, part = c & 7;
        *(uint4*)(STm + (size_t)d * STROW + 64 + row0 + part * 8) =
            *(const uint4*)(U + 16896 + d * 80 + part * 8);
      }
    }
  }
}

// ---------------------------------------------------------------------------
// fused_attn v2: 64 utterances/block, 512 thr, grid 256 (XCD-chunked swizzle).
// ph1: double-buffered global_load_lds staging (slot-XOR swizzled source +
//      read -> conflict-free ds_read_b128), Y frags prefetched to regs,
//      ONE barrier per k-step.
// softmax in registers (unchanged).
// ph2: ALL masked-A images built once in LDS ([3][64][200], conflict-free),
//      then a fully barrier-free 144-MFMA/wave K-loop with direct-global S^T.
// cross-wave log_softmax; fp32 out.
// ---------------------------------------------------------------------------
__global__ __launch_bounds__(512) void fused_attn(
    const u16* __restrict__ ws, const int* __restrict__ spk,
    float* __restrict__ out)
{
  // big: ph1 staging dbuf  [2 par][2 hi/lo][192][32]  = 24576 u16
  //      ph2 Ac            [3 rel][64][ACS=200]       = 38400 u16
  __shared__ __align__(16) u16 big[38400];
  __shared__ __align__(16) u16 Am[64 * AMS];
  __shared__ int spkw[192];
  __shared__ float prt[64][2], prs[64][2];
  __shared__ float red[64][8];

  const int t    = threadIdx.x;
  const int w    = t >> 6;
  const int ln   = t & 15;
  const int quad = (t & 63) >> 4;
  const int q8   = quad * 8;
  // XCD-chunked bijective swizzle (grid 256 % 8 == 0): 32 consecutive
  // data-blocks per XCD -> window/S^T overlap becomes same-L2 hits.
  const int bswz = (blockIdx.x & 7) * 32 + (blockIdx.x >> 3);
  const int i0   = bswz * 64;
  const int mw   = w & 3;                      // m-frag (16 rows)
  const int half = w >> 2;                     // window col half (96 each)

  if (t < 192) spkw[t] = spk[min(max(i0 - 64 + t, 0), NU - 1)];

  // ---- ph1 staging: async 16B, linear LDS dest, source slot-swizzled so the
  //      read (slot = quad ^ ((row>>1)&3)) is bank-conflict-free.
  auto STAGE = [&](int ks, int par) {
    const int kd = ks * 32;
    u16* db = big + par * 12288;
#pragma unroll
    for (int cc = 0; cc < 3; ++cc) {
      int idx  = t + 512 * cc;                 // 0..1535
      int bsel = (idx >= 768) ? 1 : 0;         // 0=hi 1=lo (wave-aligned split)
      int e    = idx - bsel * 768;
      int row  = e >> 2, s = e & 3;
      int sw   = s ^ ((row >> 1) & 3);
      int jc   = min(max(i0 + row - 64, 0), NU - 1);
      const u16* src = ws + (bsel ? XLo : XHo) + (size_t)jc * 256 + kd + sw * 8;
      u16* dst = db + bsel * 6144 + e * 8;
      gload16(src, dst);
    }
  };

  // ---- Y fragment prefetch (16 x short8 = all 8 k-steps, hi+lo) ----
  short8 yhv[8], ylv[8];
  {
    const size_t yb = (size_t)(i0 + mw * 16 + ln) * 256 + q8;
#pragma unroll
    for (int ks = 0; ks < 8; ++ks) {
      yhv[ks] = *(const short8*)(ws + YHo + yb + ks * 32);
      ylv[ks] = *(const short8*)(ws + YLo + yb + ks * 32);
    }
  }

  // ---------------- Phase 1: P = Y . Xwin^T ----------------
  floatx4 accP[6];
#pragma unroll
  for (int cc = 0; cc < 6; ++cc) accP[cc] = (floatx4){0.f, 0.f, 0.f, 0.f};

  STAGE(0, 0);
  __syncthreads();                             // drains staging (vmcnt)
#pragma unroll
  for (int ks = 0; ks < 8; ++ks) {
    if (ks < 7) STAGE(ks + 1, (ks + 1) & 1);   // prefetch overlaps compute
    const u16* sp = big + (ks & 1) * 12288;
#pragma unroll
    for (int cc = 0; cc < 6; ++cc) {
      int xrow = half * 96 + cc * 16 + ln;
      int slot = quad ^ ((xrow >> 1) & 3);
      const u16* xb = sp + xrow * 32 + slot * 8;
      short8 xbh = *(const short8*)xb;
      short8 xbl = *(const short8*)(xb + 6144);
      accP[cc] = __builtin_amdgcn_mfma_f32_16x16x32_bf16(yhv[ks], xbh, accP[cc], 0, 0, 0);
      accP[cc] = __builtin_amdgcn_mfma_f32_16x16x32_bf16(yhv[ks], xbl, accP[cc], 0, 0, 0);
      accP[cc] = __builtin_amdgcn_mfma_f32_16x16x32_bf16(ylv[ks], xbh, accP[cc], 0, 0, 0);
    }
    __syncthreads();                           // staged(ks+1) ready; reads done
  }

  // ---------------- Softmax in registers ----------------
  int  c_of[6];
  bool vj[6];
#pragma unroll
  for (int cc = 0; cc < 6; ++cc) {
    c_of[cc] = half * 96 + cc * 16 + ln;
    int j = i0 + c_of[cc] - 64;
    vj[cc] = (j >= 0) && (j < NU);
  }
#pragma unroll
  for (int r = 0; r < 4; ++r) {
    int row = mw * 16 + quad * 4 + r;
    float mx = -3.4e38f;
#pragma unroll
    for (int cc = 0; cc < 6; ++cc) {
      int rel = c_of[cc] - row;
      bool inb = (rel >= 0) && (rel < 128);
      if (inb) mx = fmaxf(mx, vj[cc] ? accP[cc][r] : 0.f);
    }
#pragma unroll
    for (int o = 1; o < 16; o <<= 1) mx = fmaxf(mx, __shfl_xor(mx, o));
    if (ln == 0) prt[row][half] = mx;
  }
  __syncthreads();
#pragma unroll
  for (int r = 0; r < 4; ++r) {
    int row = mw * 16 + quad * 4 + r;
    float gm = fmaxf(prt[row][0], prt[row][1]);
    float s = 0.f;
#pragma unroll
    for (int cc = 0; cc < 6; ++cc) {
      int rel = c_of[cc] - row;
      bool inb = (rel >= 0) && (rel < 128);
      float vv = vj[cc] ? accP[cc][r] : 0.f;
      float e  = inb ? __expf(vv - gm) : 0.f;
      s += e;                                      // padded-slot denominator
      accP[cc][r] = (inb && vj[cc]) ? e : 0.f;     // masked numerator
    }
#pragma unroll
    for (int o = 1; o < 16; o <<= 1) s += __shfl_xor(s, o);
    if (ln == 0) prs[row][half] = s;
  }
  __syncthreads();
#pragma unroll
  for (int r = 0; r < 4; ++r) {
    int row = mw * 16 + quad * 4 + r;
    float inv = 1.f / (prs[row][0] + prs[row][1]);
#pragma unroll
    for (int cc = 0; cc < 6; ++cc)
      Am[row * AMS + c_of[cc]] = bfrn(accP[cc][r] * inv);
  }
  __syncthreads();

  // ---------------- build ALL masked A images once ----------------
  // Ac[rel][row][c], rel 0=pred 1=same 2=full; stride 200 u16.
  {
    const int arow = t >> 3, aseg = t & 7;
    const int sr = spkw[arow + 64];
#pragma unroll
    for (int c6 = 0; c6 < 6; ++c6) {
      int cb = c6 * 32 + aseg * 4;
      ushort4 av = *(const ushort4*)(Am + arow * AMS + cb);
      u16 aq[4] = {av.x, av.y, av.z, av.w};
      u16 b0[4], b1[4], b2[4];
#pragma unroll
      for (int q = 0; q < 4; ++q) {
        int c = cb + q;
        b0[q] = (c - arow >= 64) ? aq[q] : (u16)0;
        b1[q] = (spkw[c] == sr) ? aq[q] : (u16)0;
        b2[q] = aq[q];
      }
      *(ushort4*)(big + 0 * ACM + arow * ACS + cb) = *(const ushort4*)b0;
      *(ushort4*)(big + 1 * ACM + arow * ACS + cb) = *(const ushort4*)b1;
      *(ushort4*)(big + 2 * ACM + arow * ACS + cb) = *(const ushort4*)b2;
    }
  }
  __syncthreads();

  // ---------------- Phase 2: aggregation (barrier-free) ----------------
  const int n0 = w * 32;
  floatx4 acc2[4][2];
#pragma unroll
  for (int m = 0; m < 4; ++m)
#pragma unroll
    for (int nt = 0; nt < 2; ++nt) acc2[m][nt] = (floatx4){0.f, 0.f, 0.f, 0.f};

  for (int kj = 0; kj < 192; kj += 32) {
#pragma unroll
    for (int rel = 0; rel < 3; ++rel) {
      short8 af[4];
#pragma unroll
      for (int m = 0; m < 4; ++m)
        af[m] = *(const short8*)(big + rel * ACM + (m * 16 + ln) * ACS + kj + q8);
#pragma unroll
      for (int nt = 0; nt < 2; ++nt) {
        size_t so = (size_t)ST0 + (size_t)rel * STMAT
                  + (size_t)(n0 + nt * 16 + ln) * STROW + (size_t)(i0 + kj) + q8;
        short8 bf8 = *(const short8*)(ws + so);
#pragma unroll
        for (int m = 0; m < 4; ++m)
          acc2[m][nt] = __builtin_amdgcn_mfma_f32_16x16x32_bf16(af[m], bf8, acc2[m][nt], 0, 0, 0);
      }
    }
  }

  // ---------------- log_softmax over 256 dims ----------------
#pragma unroll
  for (int m = 0; m < 4; ++m)
#pragma unroll
    for (int r = 0; r < 4; ++r) {
      float v = fmaxf(acc2[m][0][r], acc2[m][1][r]);
#pragma unroll
      for (int o = 1; o < 16; o <<= 1) v = fmaxf(v, __shfl_xor(v, o));
      if (ln == 0) red[m * 16 + quad * 4 + r][w] = v;
    }
  __syncthreads();
  float gmx[4][4];
#pragma unroll
  for (int m = 0; m < 4; ++m)
#pragma unroll
    for (int r = 0; r < 4; ++r) {
      int row = m * 16 + quad * 4 + r;
      float g = red[row][0];
#pragma unroll
      for (int ww = 1; ww < 8; ++ww) g = fmaxf(g, red[row][ww]);
      gmx[m][r] = g;
    }
  __syncthreads();
#pragma unroll
  for (int m = 0; m < 4; ++m)
#pragma unroll
    for (int r = 0; r < 4; ++r) {
      float e = __expf(acc2[m][0][r] - gmx[m][r]) + __expf(acc2[m][1][r] - gmx[m][r]);
#pragma unroll
      for (int o = 1; o < 16; o <<= 1) e += __shfl_xor(e, o);
      if (ln == 0) red[m * 16 + quad * 4 + r][w] = e;
    }
  __syncthreads();
#pragma unroll
  for (int m = 0; m < 4; ++m)
#pragma unroll
    for (int r = 0; r < 4; ++r) {
      int row = m * 16 + quad * 4 + r;
      float s = red[row][0];
#pragma unroll
      for (int ww = 1; ww < 8; ++ww) s += red[row][ww];
      float lse = gmx[m][r] + logf(s);
      size_t rowg = (size_t)(i0 + row) * DIM;
      out[rowg + n0 + ln]      = acc2[m][0][r] - lse;
      out[rowg + n0 + 16 + ln] = acc2[m][1][r] - lse;
    }
}

extern "C" void kernel_launch(void* const* d_in, const int* in_sizes, int n_in,
                              void* d_out, int out_size, void* d_ws, size_t ws_size,
                              hipStream_t stream) {
  const float* x   = (const float*)d_in[0];
  const int*   spk = (const int*)d_in[1];
  const float* wat = (const float*)d_in[2];
  const float* wpr = (const float*)d_in[3];
  const float* wsu = (const float*)d_in[4];
  const float* wsm = (const float*)d_in[5];
  const float* wdf = (const float*)d_in[6];
  float* out = (float*)d_out;
  u16* ws = (u16*)d_ws;    // ~68 MB used

  hipLaunchKernelGGL(xprep, dim3(2048), dim3(256), 0, stream, x, ws);
  hipLaunchKernelGGL(wpgz, dim3(128), dim3(256), 0, stream,
                     wat, wpr, wsu, wsm, wdf, ws);
  hipLaunchKernelGGL(gemmS, dim3(256, 2), dim3(512), 0, stream, ws);
  hipLaunchKernelGGL(fused_attn, dim3(256), dim3(512), 0, stream, ws, spk, out);
}

// Round 2
// 146.950 us; speedup vs baseline: 1.0509x; 1.0030x over previous
//
#include <hip/hip_runtime.h>
#include <hip/hip_bf16.h>

typedef unsigned short u16;
typedef unsigned int u32;
typedef __attribute__((ext_vector_type(8))) short short8;
typedef __attribute__((ext_vector_type(4))) float floatx4;

#define NU 16384
#define DIM 256
#define AMS 208               // Am LDS row stride (u16)
#define ACS 200               // Ac LDS row stride (u16)
#define ACM 12800             // 64 * ACS

// fused_attn LDS region offsets (u16) inside U[71680]
#define YLO 16896u            // Y lo half offset (hi at 0); X strip shares this region
#define STGo 33792u           // ph1 staging dbuf (2 x 12288)
#define AMB 58368u            // Am (64 x 208)

// ws layout (u16 offsets)
#define XHo 0u
#define XLo 4194304u
#define XRo 8388608u
#define ST0 20971520u
#define STROW 16512u          // 64 guard + 16384 + 64 guard
#define STMAT 4227072u        // 256 * STROW
#define WH0o 33652736u        // ST0 + 3*STMAT
#define WL0o 33718272u
#define WRo  33783808u        // 3 mats x 65536

__device__ __forceinline__ u16 bfh(float v) {            // truncate to bf16
  return (u16)(__float_as_uint(v) >> 16);
}
__device__ __forceinline__ float bup(u16 u) {
  return __uint_as_float(((u32)u) << 16);
}
__device__ __forceinline__ u16 bfrn(float v) {           // round-nearest-even
  u32 u = __float_as_uint(v);
  return (u16)((u + 0x7fffu + ((u >> 16) & 1u)) >> 16);
}

// async global->LDS 16B (linear wave dest: base + lane*16)
__device__ __forceinline__ void gload16(const u16* g, u16* l) {
  __builtin_amdgcn_global_load_lds(
      (__attribute__((address_space(1))) void*)(uintptr_t)g,
      (__attribute__((address_space(3))) void*)(uintptr_t)l, 16, 0, 0);
}

// ---------------------------------------------------------------------------
// prep: merged xprep + wpgz.
//  b <  2048 : xh/xl/xr images of x (8 elems/thread)
//  b >= 2048 : b2<32 weight imaging ; else S^T guard zeroing
// ---------------------------------------------------------------------------
__global__ __launch_bounds__(256) void prep(
    const float* __restrict__ x,
    const float* __restrict__ wat, const float* __restrict__ wpr,
    const float* __restrict__ wsu, const float* __restrict__ wsm,
    const float* __restrict__ wdf, u16* __restrict__ ws) {
  const int b = blockIdx.x, t = threadIdx.x;
  if (b < 2048) {
    int idx = (b * 256 + t) * 8;
    float4 v0 = *(const float4*)(x + idx);
    float4 v1 = *(const float4*)(x + idx + 4);
    float a[8] = {v0.x, v0.y, v0.z, v0.w, v1.x, v1.y, v1.z, v1.w};
    u16 h[8], l[8], r[8];
#pragma unroll
    for (int q = 0; q < 8; ++q) {
      h[q] = bfh(a[q]);
      l[q] = bfh(a[q] - bup(h[q]));
      r[q] = bfrn(a[q]);
    }
    *(uint4*)(ws + XHo + idx) = *(const uint4*)h;
    *(uint4*)(ws + XLo + idx) = *(const uint4*)l;
    *(uint4*)(ws + XRo + idx) = *(const uint4*)r;
    return;
  }
  const int b2 = b - 2048;
  if (b2 < 32) {
    const int s = b2 & 7, mat = b2 >> 3, n = t;
    const float* Wa = (mat == 0) ? wat : (mat == 1) ? wpr : (mat == 2) ? wsm : wsu;
    const float* Wb = (mat == 0) ? wat : (mat == 1) ? wsu : (mat == 2) ? wdf : wdf;
    const float c1  = (mat == 0) ? 0.f : (mat == 3) ? 1.f : -1.f;
    u16 hbuf[32], lbuf[32];
#pragma unroll 8
    for (int k = 0; k < 32; ++k) {
      float v = Wa[(s * 32 + k) * 256 + n] + c1 * Wb[(s * 32 + k) * 256 + n];
      if (mat == 0) { hbuf[k] = bfh(v); lbuf[k] = bfh(v - bup(hbuf[k])); }
      else          { hbuf[k] = bfrn(v); }
    }
    u16* dh = ws + ((mat == 0) ? WH0o : (WRo + (size_t)(mat - 1) * 65536))
               + (size_t)s * 8192 + n * 32;
#pragma unroll
    for (int p = 0; p < 4; ++p) *(uint4*)(dh + p * 8) = ((const uint4*)hbuf)[p];
    if (mat == 0) {
      u16* dl = ws + WL0o + (size_t)s * 8192 + n * 32;
#pragma unroll
      for (int p = 0; p < 4; ++p) *(uint4*)(dl + p * 8) = ((const uint4*)lbuf)[p];
    }
  } else {
    int g = (b2 - 32) * 256 + t;                   // 24576 threads
    int r = g >> 13, rem = g & 8191;
    int d = rem >> 5, p = rem & 31;
    size_t base = ST0 + (size_t)r * STMAT + (size_t)d * STROW;
    size_t off = (p < 16) ? (base + p * 4) : (base + 16448 + (p - 16) * 4);
    *(ushort4*)(ws + off) = make_ushort4(0, 0, 0, 0);
  }
}

// ---------------------------------------------------------------------------
// gemmS1: supports S1..S3 -> S^T only (Y moved into fused_attn).
// 32-row blocks, grid 512 -> 2 blocks/CU. 3 mats interleaved in ONE
// barrier-free K-loop; all 3 Ct transposes resident; single barrier.
// ---------------------------------------------------------------------------
__global__ __launch_bounds__(512, 4) void gemmS1(u16* __restrict__ ws) {
  __shared__ __align__(16) u16 U[39168];   // Ar[32*264] @0 ; Ct[3][10240] @8448

  const int t = threadIdx.x, row0 = blockIdx.x * 32;
  const int w = t >> 6, ln = t & 15, quad = (t & 63) >> 4, q8 = quad * 8;
  const int n0 = w * 32;

  // ---- stage xr strip [32][256] -> stride 264 ----
#pragma unroll
  for (int cc = 0; cc < 2; ++cc) {
    int idx = t + 512 * cc;                  // 0..1023
    int row = idx >> 5, c8 = (idx & 31) * 8;
    *(uint4*)(U + row * 264 + c8) =
        *(const uint4*)(ws + XRo + (size_t)(row0 + row) * 256 + c8);
  }
  __syncthreads();

  floatx4 acc[3][2][2];
#pragma unroll
  for (int mat = 0; mat < 3; ++mat)
#pragma unroll
    for (int m = 0; m < 2; ++m)
#pragma unroll
      for (int nt = 0; nt < 2; ++nt) acc[mat][m][nt] = (floatx4){0.f, 0.f, 0.f, 0.f};

  for (int s = 0; s < 8; ++s) {
    short8 ah[2];
#pragma unroll
    for (int m = 0; m < 2; ++m)
      ah[m] = *(const short8*)(U + (m * 16 + ln) * 264 + s * 32 + q8);
#pragma unroll
    for (int mat = 0; mat < 3; ++mat) {
      short8 bh[2];
#pragma unroll
      for (int nt = 0; nt < 2; ++nt)
        bh[nt] = *(const short8*)(ws + WRo + (size_t)mat * 65536
                                  + (size_t)s * 8192 + (n0 + nt * 16 + ln) * 32 + q8);
#pragma unroll
      for (int m = 0; m < 2; ++m)
#pragma unroll
        for (int nt = 0; nt < 2; ++nt)
          acc[mat][m][nt] = __builtin_amdgcn_mfma_f32_16x16x32_bf16(ah[m], bh[nt], acc[mat][m][nt], 0, 0, 0);
    }
  }

  // Ct writes (disjoint from Ar region; own-lane data -> no pre-barrier)
#pragma unroll
  for (int mat = 0; mat < 3; ++mat)
#pragma unroll
    for (int m = 0; m < 2; ++m)
#pragma unroll
      for (int nt = 0; nt < 2; ++nt) {
        int col = n0 + nt * 16 + ln;
        ushort4 pk = make_ushort4(bfrn(acc[mat][m][nt][0]), bfrn(acc[mat][m][nt][1]),
                                  bfrn(acc[mat][m][nt][2]), bfrn(acc[mat][m][nt][3]));
        *(ushort4*)(U + 8448 + mat * 10240 + col * 40 + m * 16 + quad * 4) = pk;
      }
  __syncthreads();

#pragma unroll
  for (int mat = 0; mat < 3; ++mat)
#pragma unroll
    for (int cc = 0; cc < 2; ++cc) {
      int c = t + 512 * cc;                  // 0..1023 : 256 d x 4 parts
      int d = c >> 2, part = c & 3;
      *(uint4*)(ws + ST0 + (size_t)mat * STMAT + (size_t)d * STROW + 64 + row0 + part * 8) =
          *(const uint4*)(U + 8448 + mat * 10240 + d * 40 + part * 8);
    }
}

// ---------------------------------------------------------------------------
// fused_attn v3: absorbs Y = X@W_att (gemmS path0).
// Phase A: stage own X strip hi/lo -> split 3-MFMA Y -> Y kept in LDS
//          (no Y HBM round-trip).
// ph1: double-buffered global_load_lds staging (swizzled), Y frags from LDS,
//      ONE barrier per k-step. softmax in registers.
// ph2: masked-A images built once ([3][64][200]); barrier-free 144-MFMA loop
//      with direct-global S^T. cross-wave log_softmax; fp32 out.
// LDS: U[71680] phase-overlapped: Xstrip/Y @0..33792, stage @33792..58368,
//      Am @58368..71680, Ac @0..38400 (after Y/stage die).
// ---------------------------------------------------------------------------
__global__ __launch_bounds__(512) void fused_attn(
    const u16* __restrict__ ws, const int* __restrict__ spk,
    float* __restrict__ out)
{
  __shared__ __align__(16) u16 U[71680];
  __shared__ int spkw[192];
  __shared__ float prt[64][2], prs[64][2];
  __shared__ float red[64][8];

  const int t    = threadIdx.x;
  const int w    = t >> 6;
  const int ln   = t & 15;
  const int quad = (t & 63) >> 4;
  const int q8   = quad * 8;
  // XCD-chunked bijective swizzle (grid 256 % 8 == 0)
  const int bswz = (blockIdx.x & 7) * 32 + (blockIdx.x >> 3);
  const int i0   = bswz * 64;
  const int mw   = w & 3;                      // ph1 m-frag (16 rows)
  const int half = w >> 2;                     // ph1 window col half (96 each)
  const int n0   = w * 32;                     // phase A / ph2 col block

  if (t < 192) spkw[t] = spk[min(max(i0 - 64 + t, 0), NU - 1)];

  // ---------------- Phase A: Y = Xstrip @ W_att (split 3-MFMA) ----------------
  {
    // stage own X strip [64][256] hi/lo -> stride 264
#pragma unroll
    for (int cc = 0; cc < 8; ++cc) {
      int idx = t + 512 * cc;                  // 0..4095
      int buf = idx >> 11, e = idx & 2047;
      int row = e >> 5, c8 = (e & 31) * 8;
      *(uint4*)(U + buf * YLO + row * 264 + c8) =
          *(const uint4*)(ws + (buf ? XLo : XHo) + (size_t)(i0 + row) * 256 + c8);
    }
    __syncthreads();

    floatx4 acc[4][2];
#pragma unroll
    for (int m = 0; m < 4; ++m)
#pragma unroll
      for (int nt = 0; nt < 2; ++nt) acc[m][nt] = (floatx4){0.f, 0.f, 0.f, 0.f};

    for (int s = 0; s < 8; ++s) {
      short8 ah[4], al[4];
#pragma unroll
      for (int m = 0; m < 4; ++m) {
        ah[m] = *(const short8*)(U + (m * 16 + ln) * 264 + s * 32 + q8);
        al[m] = *(const short8*)(U + YLO + (m * 16 + ln) * 264 + s * 32 + q8);
      }
      short8 bh[2], bl[2];
#pragma unroll
      for (int nt = 0; nt < 2; ++nt) {
        size_t off = (size_t)s * 8192 + (n0 + nt * 16 + ln) * 32 + q8;
        bh[nt] = *(const short8*)(ws + WH0o + off);
        bl[nt] = *(const short8*)(ws + WL0o + off);
      }
#pragma unroll
      for (int m = 0; m < 4; ++m)
#pragma unroll
        for (int nt = 0; nt < 2; ++nt) {
          acc[m][nt] = __builtin_amdgcn_mfma_f32_16x16x32_bf16(ah[m], bh[nt], acc[m][nt], 0, 0, 0);
          acc[m][nt] = __builtin_amdgcn_mfma_f32_16x16x32_bf16(ah[m], bl[nt], acc[m][nt], 0, 0, 0);
          acc[m][nt] = __builtin_amdgcn_mfma_f32_16x16x32_bf16(al[m], bh[nt], acc[m][nt], 0, 0, 0);
        }
    }
    __syncthreads();                           // strip reads complete

    // overwrite strip region with Y hi/lo [64][264]
#pragma unroll
    for (int m = 0; m < 4; ++m)
#pragma unroll
      for (int nt = 0; nt < 2; ++nt) {
        int col = n0 + nt * 16 + ln;
#pragma unroll
        for (int r = 0; r < 4; ++r) {
          int row = m * 16 + quad * 4 + r;
          float y = acc[m][nt][r];
          u16 hh = bfh(y);
          U[row * 264 + col] = hh;
          U[YLO + row * 264 + col] = bfh(y - bup(hh));
        }
      }
  }

  // ---- ph1 staging: async 16B, linear LDS dest, slot-swizzled source ----
  auto STAGE = [&](int ks, int par) {
    const int kd = ks * 32;
    u16* db = U + STGo + par * 12288;
#pragma unroll
    for (int cc = 0; cc < 3; ++cc) {
      int idx  = t + 512 * cc;                 // 0..1535
      int bsel = (idx >= 768) ? 1 : 0;         // 0=hi 1=lo (wave-aligned split)
      int e    = idx - bsel * 768;
      int row  = e >> 2, s = e & 3;
      int sw   = s ^ ((row >> 1) & 3);
      int jc   = min(max(i0 + row - 64, 0), NU - 1);
      const u16* src = ws + (bsel ? XLo : XHo) + (size_t)jc * 256 + kd + sw * 8;
      u16* dst = db + bsel * 6144 + e * 8;
      gload16(src, dst);
    }
  };

  // ---------------- Phase 1: P = Y . Xwin^T ----------------
  floatx4 accP[6];
#pragma unroll
  for (int cc = 0; cc < 6; ++cc) accP[cc] = (floatx4){0.f, 0.f, 0.f, 0.f};

  STAGE(0, 0);
  __syncthreads();                             // Y visible + stage0 drained
#pragma unroll
  for (int ks = 0; ks < 8; ++ks) {
    if (ks < 7) STAGE(ks + 1, (ks + 1) & 1);   // prefetch overlaps compute
    const u16* sp = U + STGo + (ks & 1) * 12288;
    const u16* yb = U + (mw * 16 + ln) * 264 + ks * 32 + q8;
    short8 yh8 = *(const short8*)yb;
    short8 yl8 = *(const short8*)(yb + YLO);
#pragma unroll
    for (int cc = 0; cc < 6; ++cc) {
      int xrow = half * 96 + cc * 16 + ln;
      int slot = quad ^ ((xrow >> 1) & 3);
      const u16* xb = sp + xrow * 32 + slot * 8;
      short8 xbh = *(const short8*)xb;
      short8 xbl = *(const short8*)(xb + 6144);
      accP[cc] = __builtin_amdgcn_mfma_f32_16x16x32_bf16(yh8, xbh, accP[cc], 0, 0, 0);
      accP[cc] = __builtin_amdgcn_mfma_f32_16x16x32_bf16(yh8, xbl, accP[cc], 0, 0, 0);
      accP[cc] = __builtin_amdgcn_mfma_f32_16x16x32_bf16(yl8, xbh, accP[cc], 0, 0, 0);
    }
    __syncthreads();                           // staged(ks+1) ready; reads done
  }

  // ---------------- Softmax in registers ----------------
  int  c_of[6];
  bool vj[6];
#pragma unroll
  for (int cc = 0; cc < 6; ++cc) {
    c_of[cc] = half * 96 + cc * 16 + ln;
    int j = i0 + c_of[cc] - 64;
    vj[cc] = (j >= 0) && (j < NU);
  }
#pragma unroll
  for (int r = 0; r < 4; ++r) {
    int row = mw * 16 + quad * 4 + r;
    float mx = -3.4e38f;
#pragma unroll
    for (int cc = 0; cc < 6; ++cc) {
      int rel = c_of[cc] - row;
      bool inb = (rel >= 0) && (rel < 128);
      if (inb) mx = fmaxf(mx, vj[cc] ? accP[cc][r] : 0.f);
    }
#pragma unroll
    for (int o = 1; o < 16; o <<= 1) mx = fmaxf(mx, __shfl_xor(mx, o));
    if (ln == 0) prt[row][half] = mx;
  }
  __syncthreads();
#pragma unroll
  for (int r = 0; r < 4; ++r) {
    int row = mw * 16 + quad * 4 + r;
    float gm = fmaxf(prt[row][0], prt[row][1]);
    float s = 0.f;
#pragma unroll
    for (int cc = 0; cc < 6; ++cc) {
      int rel = c_of[cc] - row;
      bool inb = (rel >= 0) && (rel < 128);
      float vv = vj[cc] ? accP[cc][r] : 0.f;
      float e  = inb ? __expf(vv - gm) : 0.f;
      s += e;                                      // padded-slot denominator
      accP[cc][r] = (inb && vj[cc]) ? e : 0.f;     // masked numerator
    }
#pragma unroll
    for (int o = 1; o < 16; o <<= 1) s += __shfl_xor(s, o);
    if (ln == 0) prs[row][half] = s;
  }
  __syncthreads();
#pragma unroll
  for (int r = 0; r < 4; ++r) {
    int row = mw * 16 + quad * 4 + r;
    float inv = 1.f / (prs[row][0] + prs[row][1]);
#pragma unroll
    for (int cc = 0; cc < 6; ++cc)
      U[AMB + row * AMS + c_of[cc]] = bfrn(accP[cc][r] * inv);
  }
  __syncthreads();

  // ---------------- build ALL masked A images once ----------------
  // Ac[rel][row][c] @ U[0..38400), rel 0=pred 1=same 2=full; stride 200.
  {
    const int arow = t >> 3, aseg = t & 7;
    const int sr = spkw[arow + 64];
#pragma unroll
    for (int c6 = 0; c6 < 6; ++c6) {
      int cb = c6 * 32 + aseg * 4;
      ushort4 av = *(const ushort4*)(U + AMB + arow * AMS + cb);
      u16 aq[4] = {av.x, av.y, av.z, av.w};
      u16 b0[4], b1[4], b2[4];
#pragma unroll
      for (int q = 0; q < 4; ++q) {
        int c = cb + q;
        b0[q] = (c - arow >= 64) ? aq[q] : (u16)0;
        b1[q] = (spkw[c] == sr) ? aq[q] : (u16)0;
        b2[q] = aq[q];
      }
      *(ushort4*)(U + 0 * ACM + arow * ACS + cb) = *(const ushort4*)b0;
      *(ushort4*)(U + 1 * ACM + arow * ACS + cb) = *(const ushort4*)b1;
      *(ushort4*)(U + 2 * ACM + arow * ACS + cb) = *(const ushort4*)b2;
    }
  }
  __syncthreads();

  // ---------------- Phase 2: aggregation (barrier-free) ----------------
  floatx4 acc2[4][2];
#pragma unroll
  for (int m = 0; m < 4; ++m)
#pragma unroll
    for (int nt = 0; nt < 2; ++nt) acc2[m][nt] = (floatx4){0.f, 0.f, 0.f, 0.f};

  for (int kj = 0; kj < 192; kj += 32) {
#pragma unroll
    for (int rel = 0; rel < 3; ++rel) {
      short8 af[4];
#pragma unroll
      for (int m = 0; m < 4; ++m)
        af[m] = *(const short8*)(U + rel * ACM + (m * 16 + ln) * ACS + kj + q8);
#pragma unroll
      for (int nt = 0; nt < 2; ++nt) {
        size_t so = (size_t)ST0 + (size_t)rel * STMAT
                  + (size_t)(n0 + nt * 16 + ln) * STROW + (size_t)(i0 + kj) + q8;
        short8 bf8 = *(const short8*)(ws + so);
#pragma unroll
        for (int m = 0; m < 4; ++m)
          acc2[m][nt] = __builtin_amdgcn_mfma_f32_16x16x32_bf16(af[m], bf8, acc2[m][nt], 0, 0, 0);
      }
    }
  }

  // ---------------- log_softmax over 256 dims ----------------
#pragma unroll
  for (int m = 0; m < 4; ++m)
#pragma unroll
    for (int r = 0; r < 4; ++r) {
      float v = fmaxf(acc2[m][0][r], acc2[m][1][r]);
#pragma unroll
      for (int o = 1; o < 16; o <<= 1) v = fmaxf(v, __shfl_xor(v, o));
      if (ln == 0) red[m * 16 + quad * 4 + r][w] = v;
    }
  __syncthreads();
  float gmx[4][4];
#pragma unroll
  for (int m = 0; m < 4; ++m)
#pragma unroll
    for (int r = 0; r < 4; ++r) {
      int row = m * 16 + quad * 4 + r;
      float g = red[row][0];
#pragma unroll
      for (int ww = 1; ww < 8; ++ww) g = fmaxf(g, red[row][ww]);
      gmx[m][r] = g;
    }
  __syncthreads();
#pragma unroll
  for (int m = 0; m < 4; ++m)
#pragma unroll
    for (int r = 0; r < 4; ++r) {
      float e = __expf(acc2[m][0][r] - gmx[m][r]) + __expf(acc2[m][1][r] - gmx[m][r]);
#pragma unroll
      for (int o = 1; o < 16; o <<= 1) e += __shfl_xor(e, o);
      if (ln == 0) red[m * 16 + quad * 4 + r][w] = e;
    }
  __syncthreads();
#pragma unroll
  for (int m = 0; m < 4; ++m)
#pragma unroll
    for (int r = 0; r < 4; ++r) {
      int row = m * 16 + quad * 4 + r;
      float s = red[row][0];
#pragma unroll
      for (int ww = 1; ww < 8; ++ww) s += red[row][ww];
      float lse = gmx[m][r] + logf(s);
      size_t rowg = (size_t)(i0 + row) * DIM;
      out[rowg + n0 + ln]      = acc2[m][0][r] - lse;
      out[rowg + n0 + 16 + ln] = acc2[m][1][r] - lse;
    }
}

extern "C" void kernel_launch(void* const* d_in, const int* in_sizes, int n_in,
                              void* d_out, int out_size, void* d_ws, size_t ws_size,
                              hipStream_t stream) {
  const float* x   = (const float*)d_in[0];
  const int*   spk = (const int*)d_in[1];
  const float* wat = (const float*)d_in[2];
  const float* wpr = (const float*)d_in[3];
  const float* wsu = (const float*)d_in[4];
  const float* wsm = (const float*)d_in[5];
  const float* wdf = (const float*)d_in[6];
  float* out = (float*)d_out;
  u16* ws = (u16*)d_ws;

  hipLaunchKernelGGL(prep, dim3(2176), dim3(256), 0, stream,
                     x, wat, wpr, wsu, wsm, wdf, ws);
  hipLaunchKernelGGL(gemmS1, dim3(512), dim3(512), 0, stream, ws);
  hipLaunchKernelGGL(fused_attn, dim3(256), dim3(512), 0, stream, ws, spk, out);
}